// Round 19
// baseline (613.957 us; speedup 1.0000x reference)
//
#include <hip/hip_runtime.h>
#include <hip/hip_bf16.h>
#include <math.h>

#define B_   4
#define S_   2048
#define H_   1024
#define F_   3584
#define E_   8
#define TOPK 2
#define CAP  640
#define M_   (B_*CAP)    // 2560 rows per expert
#define NTOK (B_*S_)     // 8192

typedef __attribute__((ext_vector_type(8))) short short8;
typedef __attribute__((ext_vector_type(4))) float f32x4;
typedef __attribute__((ext_vector_type(4))) unsigned short us4;

static __device__ __forceinline__ unsigned short f2bf(float f) {
  __hip_bfloat16 h = __float2bfloat16(f);
  return *reinterpret_cast<unsigned short*>(&h);
}
static __device__ __forceinline__ float bf2f(unsigned short u) {
  unsigned int x = ((unsigned int)u) << 16;
  float f;
  __builtin_memcpy(&f, &x, 4);
  return f;
}

static __device__ __forceinline__ void gload16(const void* g, void* l) {
  __builtin_amdgcn_global_load_lds((const __attribute__((address_space(1))) void*)g,
                                   (__attribute__((address_space(3))) void*)l, 16, 0, 0);
}

#define BAR() __builtin_amdgcn_s_barrier()
#define WLG() asm volatile("s_waitcnt lgkmcnt(0)" ::: "memory")
#define VM4() asm volatile("s_waitcnt vmcnt(4)" ::: "memory")
#define VM2() asm volatile("s_waitcnt vmcnt(2)" ::: "memory")
#define VM0() asm volatile("s_waitcnt vmcnt(0)" ::: "memory")

// ---------------- router (+ fused hs->bf16 conversion from registers) ----------------
__global__ __launch_bounds__(64) void k_router(const float* __restrict__ hs,
                                               const float* __restrict__ gw,
                                               int* __restrict__ e01,
                                               float* __restrict__ p01,
                                               unsigned short* __restrict__ hsb) {
  int t = blockIdx.x;
  int lane = threadIdx.x;
  const float4* xv = (const float4*)(hs + (size_t)t * H_);
  float4 xr[4];
#pragma unroll
  for (int i = 0; i < 4; ++i) xr[i] = xv[lane + i * 64];
#pragma unroll
  for (int i = 0; i < 4; ++i) {
    us4 v = {f2bf(xr[i].x), f2bf(xr[i].y), f2bf(xr[i].z), f2bf(xr[i].w)};
    *(us4*)&hsb[(size_t)t * H_ + (size_t)(lane + i * 64) * 4] = v;
  }
  float logit[E_];
#pragma unroll
  for (int e = 0; e < E_; ++e) {
    const float4* gv = (const float4*)(gw + (size_t)e * H_);
    float acc = 0.f;
#pragma unroll
    for (int i = 0; i < 4; ++i) {
      float4 g = gv[lane + i * 64];
      acc += xr[i].x * g.x + xr[i].y * g.y + xr[i].z * g.z + xr[i].w * g.w;
    }
#pragma unroll
    for (int off = 32; off > 0; off >>= 1) acc += __shfl_xor(acc, off);
    logit[e] = acc;
  }
  float mx = logit[0];
#pragma unroll
  for (int e = 1; e < E_; ++e) mx = fmaxf(mx, logit[e]);
  float p[E_], s = 0.f;
#pragma unroll
  for (int e = 0; e < E_; ++e) { p[e] = expf(logit[e] - mx); s += p[e]; }
  float inv = 1.f / s;
  int e0 = 0;
#pragma unroll
  for (int e = 1; e < E_; ++e) if (p[e] > p[e0]) e0 = e;
  int e1 = (e0 == 0) ? 1 : 0;
#pragma unroll
  for (int e = 0; e < E_; ++e) if (e != e0 && p[e] > p[e1]) e1 = e;
  if (lane == 0) {
    e01[t * 2 + 0] = e0;
    e01[t * 2 + 1] = e1;
    p01[t * 2 + 0] = p[e0] * inv;
    p01[t * 2 + 1] = p[e1] * inv;
  }
}

// ---------------- positions ----------------
__global__ __launch_bounds__(256) void k_positions(const int* __restrict__ e01,
                                                   int* __restrict__ pos,
                                                   int* __restrict__ disp) {
  int b = blockIdx.x, tid = threadIdx.x;
  __shared__ unsigned char eid[S_ * TOPK];
  __shared__ int part[256];
  for (int i = tid; i < E_ * CAP; i += 256)
    disp[((size_t)(i / CAP) * B_ + b) * CAP + (i % CAP)] = -1;
  for (int i = tid; i < S_ * TOPK; i += 256)
    eid[i] = (unsigned char)e01[b * S_ * TOPK + i];
  __syncthreads();
  const int per = (S_ * TOPK) / 256;  // 16
  int base = tid * per;
  for (int e = 0; e < E_; ++e) {
    int cnt = 0;
    for (int j = 0; j < per; ++j) cnt += (eid[base + j] == e) ? 1 : 0;
    part[tid] = cnt;
    __syncthreads();
    for (int off = 1; off < 256; off <<= 1) {
      int v = part[tid];
      int add = (tid >= off) ? part[tid - off] : 0;
      __syncthreads();
      part[tid] = v + add;
      __syncthreads();
    }
    int run = part[tid] - cnt;
    for (int j = 0; j < per; ++j) {
      int sl = base + j;
      if (eid[sl] == e) {
        ++run;
        int p = (run <= CAP) ? (run - 1) : -1;
        pos[b * S_ * TOPK + sl] = p;
        if (p >= 0) disp[((size_t)e * B_ + b) * CAP + p] = sl >> 1;
      }
    }
    __syncthreads();
  }
}

// ---------------- weight transpose + f32->bf16 (optional 16-row interleave) ----------------
__global__ __launch_bounds__(256) void k_transpose(const float* __restrict__ in,
                                                   unsigned short* __restrict__ outp,
                                                   int R, int C, int ileave, int half,
                                                   size_t ostride_e) {
  __shared__ unsigned short ls[64][72];
  int e = blockIdx.z, tc = blockIdx.x, tr = blockIdx.y, tid = threadIdx.x;
  const float* src = in + (size_t)e * R * C + (size_t)tr * 64 * C + (size_t)tc * 64;
#pragma unroll
  for (int i = 0; i < 16; ++i) {
    int row = i * 4 + (tid >> 6), col = tid & 63;
    ls[row][col] = f2bf(src[(size_t)row * C + col]);
  }
  __syncthreads();
  unsigned short* dbase = outp + (size_t)e * ostride_e;
#pragma unroll
  for (int i = 0; i < 4; ++i) {
    int orow = i * 16 + (tid >> 4), oc = (tid & 15) * 4;
    int gr = tc * 64 + orow;
    int ri = ileave ? ((gr & ~15) * 2 + (gr & 15) + half * 16) : gr;
    us4 v = {ls[oc + 0][orow], ls[oc + 1][orow], ls[oc + 2][orow], ls[oc + 3][orow]};
    *(us4*)&dbase[(size_t)ri * R + tr * 64 + oc] = v;
  }
}

// ================= GEMM1: 256x256, 1024 threads (16 waves, 4 waves/SIMD) =================
// GATHER-A from hsb via disp; SwiGLU epilogue. Measured 299 us (round 18).
#define STAGE_A10(d, h, t) {                                                  \
    gload16(pA0 + (size_t)(t) * 64 + (h) * 32, &lds[((d) * 2 + (h)) * 8192 + tid * 8]); \
  }
#define STAGE_B10(d, h, t) {                                                  \
    gload16(srcB + (size_t)(t) * 64 + (h) * 32, &lds[32768 + ((d) * 2 + (h)) * 8192 + tid * 8]); \
  }
#define RD_A10(d, h) {                                                        \
    const unsigned short* _pa = &lds[((d) * 2 + (h)) * 8192 + aoff];          \
    _Pragma("unroll") for (int m = 0; m < 4; ++m)                             \
      a[m] = *(const short8*)&_pa[m * 512];                                   \
  }
#define RD_B10(d, h) {                                                        \
    const unsigned short* _pb = &lds[32768 + ((d) * 2 + (h)) * 8192 + boff];  \
    _Pragma("unroll") for (int n = 0; n < 4; ++n)                             \
      b[n] = *(const short8*)&_pb[n * 512];                                   \
  }
#define MFMA10() {                                                            \
    __builtin_amdgcn_s_setprio(1);                                            \
    _Pragma("unroll") for (int m = 0; m < 4; ++m)                             \
      _Pragma("unroll") for (int n = 0; n < 4; ++n)                           \
        acc[m][n] = __builtin_amdgcn_mfma_f32_16x16x32_bf16(a[m], b[n], acc[m][n], 0, 0, 0); \
    __builtin_amdgcn_s_setprio(0);                                            \
  }
#define BODY10(P, tn) {                                                       \
    RD_A10(P, 0); RD_B10(P, 0); STAGE_A10((P) ^ 1, 0, tn); STAGE_B10((P) ^ 1, 0, tn); \
    WLG(); MFMA10(); VM2(); BAR();                                            \
    RD_A10(P, 1); RD_B10(P, 1); STAGE_A10((P) ^ 1, 1, tn); STAGE_B10((P) ^ 1, 1, tn); \
    WLG(); MFMA10(); VM2(); BAR();                                            \
  }
#define PEEL10(P) {                                                           \
    RD_A10(P, 0); RD_B10(P, 0);                                               \
    WLG(); MFMA10(); VM0(); BAR();                                            \
    RD_A10(P, 1); RD_B10(P, 1);                                               \
    WLG(); MFMA10();                                                          \
  }

template <int KTOT, int MT, int NTN, int NTOTB>
__global__ __launch_bounds__(1024, 4) void k_gemm1(const unsigned short* __restrict__ Aall,
                                                   const unsigned short* __restrict__ Ball,
                                                   unsigned short* __restrict__ Cout,
                                                   const int* __restrict__ disp) {
  constexpr int NT = KTOT / 64;
  __shared__ __align__(16) unsigned short lds[65536];

  const int nwg = MT * NTN * E_;
  int lid = blockIdx.x;
  int sw = (lid & 7) * (nwg >> 3) + (lid >> 3);
  constexpr int PER = MT * NTN;
  int e = sw / PER;
  int rem = sw - e * PER;
  int tn = rem / MT, tm = rem - tn * MT;

  int tid = threadIdx.x, li = tid & 63, wid = tid >> 6;
  int wm = wid >> 2, wn = wid & 3;

  int rS = tid >> 2;
  int gS = (tid & 3) ^ ((tid >> 3) & 3);
  int r0 = tm * 256 + rS;
  int b0 = r0 / CAP;
  int tok0 = disp[(size_t)e * B_ * CAP + r0];
  if (tok0 < 0) tok0 = 0;
  const unsigned short* pA0 = Aall + ((size_t)b0 * S_ + tok0) * H_ + gS * 8;
  const unsigned short* srcB = Ball + ((size_t)e * NTOTB + (size_t)tn * 256 + rS) * KTOT + gS * 8;

  int sA = (li >> 4) ^ ((li >> 1) & 3);
  int aoff = (wm * 64 + (li & 15)) * 32 + sA * 8;
  int boff = (wn * 64 + (li & 15)) * 32 + sA * 8;

  f32x4 acc[4][4] = {};
  short8 a[4], b[4];

  STAGE_A10(0, 0, 0); STAGE_B10(0, 0, 0);
  STAGE_A10(0, 1, 0); STAGE_B10(0, 1, 0);
  VM2();
  BAR();

#pragma unroll 1
  for (int t = 0; t + 1 < NT - 1; t += 2) {
    BODY10(0, t + 1);
    BODY10(1, t + 2);
  }
  if constexpr (((NT - 1) & 1) != 0) {
    BODY10(0, NT - 1);
  }
  if constexpr (((NT - 1) & 1) != 0) {
    PEEL10(1);
  } else {
    PEEL10(0);
  }

  int r0o = tm * 256 + wm * 64 + ((li >> 4) << 2);
  unsigned short* out = Cout + (size_t)e * M_ * F_;
#pragma unroll
  for (int m = 0; m < 4; ++m)
#pragma unroll
    for (int u = 0; u < 2; ++u) {
      int col = (tn * 8 + wn * 2 + u) * 16 + (li & 15);
#pragma unroll
      for (int j = 0; j < 4; ++j) {
        float h1 = acc[m][2 * u][j], h3 = acc[m][2 * u + 1][j];
        float sg = 1.f / (1.f + __expf(-h1));
        out[(size_t)(r0o + m * 16 + j) * F_ + col] = f2bf(h1 * sg * h3);
      }
    }
}

// ================= GEMM2: 256x256, 512 threads (round-14 schedule), split-K =================
#define STAGE_A5(d, h, t) {                                                   \
    size_t _o = (size_t)(t) * 64 + (h) * 32;                                  \
    gload16(pA0 + _o, &lds[((d) * 2 + (h)) * 8192 + tid * 8]);                \
    gload16(pA1 + _o, &lds[((d) * 2 + (h)) * 8192 + tid * 8 + 4096]);         \
  }
#define STAGE_B5(d, h, t) {                                                   \
    size_t _o = (size_t)(t) * 64 + (h) * 32;                                  \
    gload16(srcB + _o, &lds[32768 + ((d) * 2 + (h)) * 8192 + tid * 8]);       \
    gload16(srcB + (size_t)128 * KTOT + _o, &lds[32768 + ((d) * 2 + (h)) * 8192 + tid * 8 + 4096]); \
  }
#define RD_A5(d, h, mh) {                                                     \
    const unsigned short* _pa = &lds[((d) * 2 + (h)) * 8192 + aoff + (mh) * 2048]; \
    _Pragma("unroll") for (int j = 0; j < 4; ++j)                             \
      a[j] = *(const short8*)&_pa[j * 512];                                   \
  }
#define RD_B5(d, h) {                                                         \
    const unsigned short* _pb = &lds[32768 + ((d) * 2 + (h)) * 8192 + boff];  \
    _Pragma("unroll") for (int n = 0; n < 4; ++n)                             \
      b[n] = *(const short8*)&_pb[n * 512];                                   \
  }
#define MFMA5(mh) {                                                           \
    __builtin_amdgcn_s_setprio(1);                                            \
    _Pragma("unroll") for (int j = 0; j < 4; ++j)                             \
      _Pragma("unroll") for (int n = 0; n < 4; ++n)                           \
        acc[(mh) * 4 + j][n] = __builtin_amdgcn_mfma_f32_16x16x32_bf16(a[j], b[n], acc[(mh) * 4 + j][n], 0, 0, 0); \
    __builtin_amdgcn_s_setprio(0);                                            \
  }
#define BODY5(P, tn) {                                                        \
    RD_A5(P, 0, 0); RD_B5(P, 0); STAGE_A5((P) ^ 1, 0, tn);                    \
    WLG(); MFMA5(0); BAR();                                                   \
    RD_A5(P, 0, 1); STAGE_B5((P) ^ 1, 0, tn);                                 \
    WLG(); MFMA5(1); VM4(); BAR();                                            \
    RD_A5(P, 1, 0); RD_B5(P, 1); STAGE_A5((P) ^ 1, 1, tn);                    \
    WLG(); MFMA5(0); BAR();                                                   \
    RD_A5(P, 1, 1); STAGE_B5((P) ^ 1, 1, tn);                                 \
    WLG(); MFMA5(1); VM4(); BAR();                                            \
  }
#define PEEL5(P) {                                                            \
    RD_A5(P, 0, 0); RD_B5(P, 0);                                              \
    WLG(); MFMA5(0); BAR();                                                   \
    RD_A5(P, 0, 1);                                                           \
    WLG(); MFMA5(1); VM0(); BAR();                                            \
    RD_A5(P, 1, 0); RD_B5(P, 1);                                              \
    WLG(); MFMA5(0); BAR();                                                   \
    RD_A5(P, 1, 1);                                                           \
    WLG(); MFMA5(1);                                                          \
  }

template <int KTOT, int MT, int NTN, int NTOTB, int SPLITK>
__global__ __launch_bounds__(512, 2) void k_gemm2(const unsigned short* __restrict__ Aall,
                                                  const unsigned short* __restrict__ Ball,
                                                  unsigned short* __restrict__ Cout) {
  constexpr int KSUB = KTOT / SPLITK;
  constexpr int NT = KSUB / 64;
  __shared__ __align__(16) unsigned short lds[65536];

  const int nwg = MT * NTN * E_ * SPLITK;
  int lid = blockIdx.x;
  int sw = (lid & 7) * (nwg >> 3) + (lid >> 3);
  constexpr int PER = MT * NTN;
  int ks = sw / (PER * E_);
  int rem2 = sw - ks * (PER * E_);
  int e = rem2 / PER;
  int rem = rem2 - e * PER;
  int tn = rem / MT, tm = rem - tn * MT;

  int tid = threadIdx.x, li = tid & 63, wid = tid >> 6;
  int wm = wid >> 2, wn = wid & 3;

  int rS = tid >> 2;
  int gS = (tid & 3) ^ ((tid >> 3) & 3);
  const unsigned short* pA0 = Aall + ((size_t)e * M_ + (size_t)tm * 256 + rS) * KTOT + ks * KSUB + gS * 8;
  const unsigned short* pA1 = pA0 + (size_t)128 * KTOT;
  const unsigned short* srcB = Ball + ((size_t)e * NTOTB + (size_t)tn * 256 + rS) * KTOT + ks * KSUB + gS * 8;

  int sA = (li >> 4) ^ ((li >> 1) & 3);
  int aoff = (wm * 128 + (li & 15)) * 32 + sA * 8;
  int boff = (wn * 64 + (li & 15)) * 32 + sA * 8;

  f32x4 acc[8][4] = {};
  short8 a[4], b[4];

  STAGE_A5(0, 0, 0); STAGE_B5(0, 0, 0);
  STAGE_A5(0, 1, 0); STAGE_B5(0, 1, 0);
  VM4();
  BAR();

#pragma unroll 1
  for (int t = 0; t + 1 < NT - 1; t += 2) {
    BODY5(0, t + 1);
    BODY5(1, t + 2);
  }
  if constexpr (((NT - 1) & 1) != 0) {
    BODY5(0, NT - 1);
  }
  if constexpr (((NT - 1) & 1) != 0) {
    PEEL5(1);
  } else {
    PEEL5(0);
  }

  int r0o = tm * 256 + wm * 128 + ((li >> 4) << 2);
  unsigned short* out = Cout + ((size_t)ks * E_ + e) * M_ * NTOTB;
#pragma unroll
  for (int m = 0; m < 8; ++m)
#pragma unroll
    for (int n = 0; n < 4; ++n) {
      int col = tn * 256 + wn * 64 + n * 16 + (li & 15);
#pragma unroll
      for (int j = 0; j < 4; ++j)
        out[(size_t)(r0o + m * 16 + j) * NTOTB + col] = f2bf(acc[m][n][j]);
    }
}

// ---------------- combine (sums the two split-K partials) ----------------
__global__ __launch_bounds__(256) void k_combine(const unsigned short* __restrict__ Oe0,
                                                 const unsigned short* __restrict__ Oe1,
                                                 const int* __restrict__ e01,
                                                 const float* __restrict__ p01,
                                                 const int* __restrict__ pos,
                                                 float* __restrict__ outp) {
  int t = blockIdx.x;
  int b = t / S_;
  int tid = threadIdx.x;
  float4 acc = {0.f, 0.f, 0.f, 0.f};
#pragma unroll
  for (int k = 0; k < TOPK; ++k) {
    int p = pos[t * 2 + k];
    if (p >= 0) {
      int e = e01[t * 2 + k];
      float w = p01[t * 2 + k];
      size_t row = (size_t)e * M_ + (size_t)b * CAP + p;
      us4 v0 = *(const us4*)&Oe0[row * H_ + tid * 4];
      us4 v1 = *(const us4*)&Oe1[row * H_ + tid * 4];
      acc.x += w * (bf2f(v0[0]) + bf2f(v1[0]));
      acc.y += w * (bf2f(v0[1]) + bf2f(v1[1]));
      acc.z += w * (bf2f(v0[2]) + bf2f(v1[2]));
      acc.w += w * (bf2f(v0[3]) + bf2f(v1[3]));
    }
  }
  *(float4*)&outp[(size_t)t * H_ + tid * 4] = acc;
}

extern "C" void kernel_launch(void* const* d_in, const int* in_sizes, int n_in,
                              void* d_out, int out_size, void* d_ws, size_t ws_size,
                              hipStream_t stream) {
  const float* hs = (const float*)d_in[0];
  const float* gw = (const float*)d_in[1];
  const float* w1 = (const float*)d_in[2];
  const float* w2 = (const float*)d_in[3];
  const float* w3 = (const float*)d_in[4];

  char* ws = (char*)d_ws;
  size_t off = 0;
  auto take = [&](size_t bytes) -> char* {
    char* p = ws + off;
    off += (bytes + 255) & ~(size_t)255;
    return p;
  };
  int*            e01  = (int*)take((size_t)NTOK * 2 * 4);
  float*          p01  = (float*)take((size_t)NTOK * 2 * 4);
  int*            pos  = (int*)take((size_t)NTOK * 2 * 4);
  int*            disp = (int*)take((size_t)E_ * B_ * CAP * 4);
  unsigned short* w13t = (unsigned short*)take((size_t)E_ * 2 * F_ * H_ * 2);
  unsigned short* w2t  = (unsigned short*)take((size_t)E_ * H_ * F_ * 2);
  unsigned short* hsb  = (unsigned short*)take((size_t)NTOK * H_ * 2);
  unsigned short* act  = (unsigned short*)take((size_t)E_ * M_ * F_ * 2);
  unsigned short* oe   = (unsigned short*)take((size_t)2 * E_ * M_ * H_ * 2);  // 2 split-K partials

  k_router<<<NTOK, 64, 0, stream>>>(hs, gw, e01, p01, hsb);
  k_positions<<<B_, 256, 0, stream>>>(e01, pos, disp);
  k_transpose<<<dim3(F_ / 64, H_ / 64, E_), 256, 0, stream>>>(w1, w13t, H_, F_, 1, 0, (size_t)2 * F_ * H_);
  k_transpose<<<dim3(F_ / 64, H_ / 64, E_), 256, 0, stream>>>(w3, w13t, H_, F_, 1, 1, (size_t)2 * F_ * H_);
  k_transpose<<<dim3(H_ / 64, F_ / 64, E_), 256, 0, stream>>>(w2, w2t, F_, H_, 0, 0, (size_t)H_ * F_);
  // GEMM1 (1024 thr, 4 waves/SIMD): gather-A from hsb; [M_ x 2F] over K=H, SwiGLU -> act
  k_gemm1<H_, M_ / 256, (2 * F_) / 256, 2 * F_>
      <<<(M_ / 256) * ((2 * F_) / 256) * E_, 1024, 0, stream>>>(hsb, w13t, act, disp);
  // GEMM2 (512 thr, round-14 schedule): [M_ x H] over K=F, split-K=2
  k_gemm2<F_, M_ / 256, H_ / 256, H_, 2>
      <<<(M_ / 256) * (H_ / 256) * E_ * 2, 512, 0, stream>>>(act, w2t, oe);
  k_combine<<<NTOK, 256, 0, stream>>>(oe, oe + (size_t)E_ * M_ * H_, e01, p01, pos, (float*)d_out);
}

// Round 20
// 574.709 us; speedup vs baseline: 1.0683x; 1.0683x over previous
//
#include <hip/hip_runtime.h>
#include <hip/hip_bf16.h>
#include <math.h>

#define B_   4
#define S_   2048
#define H_   1024
#define F_   3584
#define E_   8
#define TOPK 2
#define CAP  640
#define M_   (B_*CAP)    // 2560 rows per expert
#define NTOK (B_*S_)     // 8192

typedef __attribute__((ext_vector_type(8))) short short8;
typedef __attribute__((ext_vector_type(4))) float f32x4;
typedef __attribute__((ext_vector_type(4))) unsigned short us4;

static __device__ __forceinline__ unsigned short f2bf(float f) {
  __hip_bfloat16 h = __float2bfloat16(f);
  return *reinterpret_cast<unsigned short*>(&h);
}
static __device__ __forceinline__ float bf2f(unsigned short u) {
  unsigned int x = ((unsigned int)u) << 16;
  float f;
  __builtin_memcpy(&f, &x, 4);
  return f;
}

static __device__ __forceinline__ void gload16(const void* g, void* l) {
  __builtin_amdgcn_global_load_lds((const __attribute__((address_space(1))) void*)g,
                                   (__attribute__((address_space(3))) void*)l, 16, 0, 0);
}

#define BAR() __builtin_amdgcn_s_barrier()
#define WLG() asm volatile("s_waitcnt lgkmcnt(0)" ::: "memory")
#define VM4() asm volatile("s_waitcnt vmcnt(4)" ::: "memory")
#define VM0() asm volatile("s_waitcnt vmcnt(0)" ::: "memory")

// ---------------- router (+ fused hs->bf16 conversion from registers) ----------------
__global__ __launch_bounds__(64) void k_router(const float* __restrict__ hs,
                                               const float* __restrict__ gw,
                                               int* __restrict__ e01,
                                               float* __restrict__ p01,
                                               unsigned short* __restrict__ hsb) {
  int t = blockIdx.x;
  int lane = threadIdx.x;
  const float4* xv = (const float4*)(hs + (size_t)t * H_);
  float4 xr[4];
#pragma unroll
  for (int i = 0; i < 4; ++i) xr[i] = xv[lane + i * 64];
#pragma unroll
  for (int i = 0; i < 4; ++i) {
    us4 v = {f2bf(xr[i].x), f2bf(xr[i].y), f2bf(xr[i].z), f2bf(xr[i].w)};
    *(us4*)&hsb[(size_t)t * H_ + (size_t)(lane + i * 64) * 4] = v;
  }
  float logit[E_];
#pragma unroll
  for (int e = 0; e < E_; ++e) {
    const float4* gv = (const float4*)(gw + (size_t)e * H_);
    float acc = 0.f;
#pragma unroll
    for (int i = 0; i < 4; ++i) {
      float4 g = gv[lane + i * 64];
      acc += xr[i].x * g.x + xr[i].y * g.y + xr[i].z * g.z + xr[i].w * g.w;
    }
#pragma unroll
    for (int off = 32; off > 0; off >>= 1) acc += __shfl_xor(acc, off);
    logit[e] = acc;
  }
  float mx = logit[0];
#pragma unroll
  for (int e = 1; e < E_; ++e) mx = fmaxf(mx, logit[e]);
  float p[E_], s = 0.f;
#pragma unroll
  for (int e = 0; e < E_; ++e) { p[e] = expf(logit[e] - mx); s += p[e]; }
  float inv = 1.f / s;
  int e0 = 0;
#pragma unroll
  for (int e = 1; e < E_; ++e) if (p[e] > p[e0]) e0 = e;
  int e1 = (e0 == 0) ? 1 : 0;
#pragma unroll
  for (int e = 0; e < E_; ++e) if (e != e0 && p[e] > p[e1]) e1 = e;
  if (lane == 0) {
    e01[t * 2 + 0] = e0;
    e01[t * 2 + 1] = e1;
    p01[t * 2 + 0] = p[e0] * inv;
    p01[t * 2 + 1] = p[e1] * inv;
  }
}

// ---------------- positions ----------------
__global__ __launch_bounds__(256) void k_positions(const int* __restrict__ e01,
                                                   int* __restrict__ pos,
                                                   int* __restrict__ disp) {
  int b = blockIdx.x, tid = threadIdx.x;
  __shared__ unsigned char eid[S_ * TOPK];
  __shared__ int part[256];
  for (int i = tid; i < E_ * CAP; i += 256)
    disp[((size_t)(i / CAP) * B_ + b) * CAP + (i % CAP)] = -1;
  for (int i = tid; i < S_ * TOPK; i += 256)
    eid[i] = (unsigned char)e01[b * S_ * TOPK + i];
  __syncthreads();
  const int per = (S_ * TOPK) / 256;  // 16
  int base = tid * per;
  for (int e = 0; e < E_; ++e) {
    int cnt = 0;
    for (int j = 0; j < per; ++j) cnt += (eid[base + j] == e) ? 1 : 0;
    part[tid] = cnt;
    __syncthreads();
    for (int off = 1; off < 256; off <<= 1) {
      int v = part[tid];
      int add = (tid >= off) ? part[tid - off] : 0;
      __syncthreads();
      part[tid] = v + add;
      __syncthreads();
    }
    int run = part[tid] - cnt;
    for (int j = 0; j < per; ++j) {
      int sl = base + j;
      if (eid[sl] == e) {
        ++run;
        int p = (run <= CAP) ? (run - 1) : -1;
        pos[b * S_ * TOPK + sl] = p;
        if (p >= 0) disp[((size_t)e * B_ + b) * CAP + p] = sl >> 1;
      }
    }
    __syncthreads();
  }
}

// ---------------- weight transpose + f32->bf16 (vectorized float4 reads) ----------------
__global__ __launch_bounds__(256) void k_transpose(const float* __restrict__ in,
                                                   unsigned short* __restrict__ outp,
                                                   int R, int C, int ileave, int half,
                                                   size_t ostride_e) {
  __shared__ unsigned short ls[64][72];
  int e = blockIdx.z, tc = blockIdx.x, tr = blockIdx.y, tid = threadIdx.x;
  const float* src = in + (size_t)e * R * C + (size_t)tr * 64 * C + (size_t)tc * 64;
  // vectorized read: 16 threads x float4 cover one 64-col row segment (16B/lane)
#pragma unroll
  for (int i = 0; i < 4; ++i) {
    int row = i * 16 + (tid >> 4), c4 = (tid & 15) * 4;
    float4 f = *(const float4*)&src[(size_t)row * C + c4];
    us4 v = {f2bf(f.x), f2bf(f.y), f2bf(f.z), f2bf(f.w)};
    *(us4*)&ls[row][c4] = v;
  }
  __syncthreads();
  unsigned short* dbase = outp + (size_t)e * ostride_e;
#pragma unroll
  for (int i = 0; i < 4; ++i) {
    int orow = i * 16 + (tid >> 4), oc = (tid & 15) * 4;
    int gr = tc * 64 + orow;
    int ri = ileave ? ((gr & ~15) * 2 + (gr & 15) + half * 16) : gr;
    us4 v = {ls[oc + 0][orow], ls[oc + 1][orow], ls[oc + 2][orow], ls[oc + 3][orow]};
    *(us4*)&dbase[(size_t)ri * R + tr * 64 + oc] = v;
  }
}

// ---------------- 256x256 GEMM, round-14 schedule (single barrier per phase) ----------------
// A: GATHER ? per-row indirect from hsb via disp : linear [E][M_][KTOT] bf16
// B: [E][NTOTB][KTOT] bf16 (N-major, K contiguous)
// Per K-tile (BK=64): 4 phases = (kk-half x m-half), 16 MFMA each, one STAGE
// (2 gloads)/phase, vmcnt(4) gates in P1/P3, one barrier per phase.
// LDS: A regions (d,h) 16KiB at (d*2+h)*8192 us; B at 32768+(d*2+h)*8192. 128 KiB.
#define STAGE_A(d, h, t) {                                                    \
    size_t _o = (size_t)(t) * 64 + (h) * 32;                                  \
    gload16(pA0 + _o, &lds[((d) * 2 + (h)) * 8192 + tid * 8]);                \
    gload16(pA1 + _o, &lds[((d) * 2 + (h)) * 8192 + tid * 8 + 4096]);         \
  }
#define STAGE_B(d, h, t) {                                                    \
    size_t _o = (size_t)(t) * 64 + (h) * 32;                                  \
    gload16(srcB + _o, &lds[32768 + ((d) * 2 + (h)) * 8192 + tid * 8]);       \
    gload16(srcB + (size_t)128 * KTOT + _o, &lds[32768 + ((d) * 2 + (h)) * 8192 + tid * 8 + 4096]); \
  }
#define RD_A4(d, h, mh) {                                                     \
    const unsigned short* _pa = &lds[((d) * 2 + (h)) * 8192 + aoff + (mh) * 2048]; \
    _Pragma("unroll") for (int j = 0; j < 4; ++j)                             \
      a[j] = *(const short8*)&_pa[j * 512];                                   \
  }
#define RD_B4(d, h) {                                                         \
    const unsigned short* _pb = &lds[32768 + ((d) * 2 + (h)) * 8192 + boff];  \
    _Pragma("unroll") for (int n = 0; n < 4; ++n)                             \
      b[n] = *(const short8*)&_pb[n * 512];                                   \
  }
#define MFMA16(mh) {                                                          \
    __builtin_amdgcn_s_setprio(1);                                            \
    _Pragma("unroll") for (int j = 0; j < 4; ++j)                             \
      _Pragma("unroll") for (int n = 0; n < 4; ++n)                           \
        acc[(mh) * 4 + j][n] = __builtin_amdgcn_mfma_f32_16x16x32_bf16(a[j], b[n], acc[(mh) * 4 + j][n], 0, 0, 0); \
    __builtin_amdgcn_s_setprio(0);                                            \
  }
#define BODY(P, tn) {                                                         \
    RD_A4(P, 0, 0); RD_B4(P, 0); STAGE_A((P) ^ 1, 0, tn);                     \
    WLG(); MFMA16(0); BAR();                                                  \
    RD_A4(P, 0, 1); STAGE_B((P) ^ 1, 0, tn);                                  \
    WLG(); MFMA16(1); VM4(); BAR();                                           \
    RD_A4(P, 1, 0); RD_B4(P, 1); STAGE_A((P) ^ 1, 1, tn);                     \
    WLG(); MFMA16(0); BAR();                                                  \
    RD_A4(P, 1, 1); STAGE_B((P) ^ 1, 1, tn);                                  \
    WLG(); MFMA16(1); VM4(); BAR();                                           \
  }
#define PEEL(P) {                                                             \
    RD_A4(P, 0, 0); RD_B4(P, 0);                                              \
    WLG(); MFMA16(0); BAR();                                                  \
    RD_A4(P, 0, 1);                                                           \
    WLG(); MFMA16(1); VM0(); BAR();                                           \
    RD_A4(P, 1, 0); RD_B4(P, 1);                                              \
    WLG(); MFMA16(0); BAR();                                                  \
    RD_A4(P, 1, 1);                                                           \
    WLG(); MFMA16(1);                                                         \
  }

template <int KTOT, bool SWIGLU, bool GATHER, int MT, int NTN, int NTOTB, int SPLITK>
__global__ __launch_bounds__(512, 2) void k_gemm256(const unsigned short* __restrict__ Aall,
                                                    const unsigned short* __restrict__ Ball,
                                                    unsigned short* __restrict__ Cout,
                                                    const int* __restrict__ disp) {
  constexpr int KSUB = KTOT / SPLITK;
  constexpr int NT = KSUB / 64;
  __shared__ __align__(16) unsigned short lds[65536];  // 128 KiB

  const int nwg = MT * NTN * E_ * SPLITK;
  int lid = blockIdx.x;
  int sw = (lid & 7) * (nwg >> 3) + (lid >> 3);  // XCD swizzle (nwg%8==0)
  constexpr int PER = MT * NTN;
  int ks = sw / (PER * E_);
  int rem2 = sw - ks * (PER * E_);
  int e = rem2 / PER;
  int rem = rem2 - e * PER;
  int tn = rem / MT, tm = rem - tn * MT;

  int tid = threadIdx.x, li = tid & 63, wid = tid >> 6;
  int wm = wid >> 2, wn = wid & 3;

  // stage-side per-thread source (inverse-swizzled global address, rule #21)
  int rS = tid >> 2;
  int gS = (tid & 3) ^ ((tid >> 3) & 3);
  const unsigned short* pA0;
  const unsigned short* pA1;
  if constexpr (GATHER) {
    int r0 = tm * 256 + rS;
    int r1 = r0 + 128;
    int b0 = r0 / CAP, b1 = r1 / CAP;
    int tok0 = disp[(size_t)e * B_ * CAP + r0];
    int tok1 = disp[(size_t)e * B_ * CAP + r1];
    if (tok0 < 0) tok0 = 0;  // dead slot: output never read
    if (tok1 < 0) tok1 = 0;
    pA0 = Aall + ((size_t)b0 * S_ + tok0) * H_ + ks * KSUB + gS * 8;
    pA1 = Aall + ((size_t)b1 * S_ + tok1) * H_ + ks * KSUB + gS * 8;
  } else {
    const unsigned short* srcA = Aall + ((size_t)e * M_ + (size_t)tm * 256 + rS) * KTOT + ks * KSUB + gS * 8;
    pA0 = srcA;
    pA1 = srcA + (size_t)128 * KTOT;
  }
  const unsigned short* srcB = Ball + ((size_t)e * NTOTB + (size_t)tn * 256 + rS) * KTOT + ks * KSUB + gS * 8;

  // read-side swizzled offsets (ushort units)
  int sA = (li >> 4) ^ ((li >> 1) & 3);
  int aoff = (wm * 128 + (li & 15)) * 32 + sA * 8;
  int boff = (wn * 64 + (li & 15)) * 32 + sA * 8;

  f32x4 acc[8][4] = {};
  short8 a[4], b[4];

  // prologue: tile0 all 4 halves into region 0
  STAGE_A(0, 0, 0); STAGE_B(0, 0, 0);
  STAGE_A(0, 1, 0); STAGE_B(0, 1, 0);
  VM4();
  BAR();

#pragma unroll 1
  for (int t = 0; t + 1 < NT - 1; t += 2) {
    BODY(0, t + 1);
    BODY(1, t + 2);
  }
  if constexpr (((NT - 1) & 1) != 0) {
    BODY(0, NT - 1);
  }
  if constexpr (((NT - 1) & 1) != 0) {
    PEEL(1);
  } else {
    PEEL(0);
  }

  // epilogue
  int r0o = tm * 256 + wm * 128 + ((li >> 4) << 2);
  if constexpr (SWIGLU) {
    unsigned short* out = Cout + (size_t)e * M_ * F_;
#pragma unroll
    for (int m = 0; m < 8; ++m)
#pragma unroll
      for (int u = 0; u < 2; ++u) {
        int col = (tn * 8 + wn * 2 + u) * 16 + (li & 15);
#pragma unroll
        for (int j = 0; j < 4; ++j) {
          float h1 = acc[m][2 * u][j], h3 = acc[m][2 * u + 1][j];
          float sg = 1.f / (1.f + __expf(-h1));
          out[(size_t)(r0o + m * 16 + j) * F_ + col] = f2bf(h1 * sg * h3);
        }
      }
  } else {
    unsigned short* out = Cout + ((size_t)ks * E_ + e) * M_ * NTOTB;
#pragma unroll
    for (int m = 0; m < 8; ++m)
#pragma unroll
      for (int n = 0; n < 4; ++n) {
        int col = tn * 256 + wn * 64 + n * 16 + (li & 15);
#pragma unroll
        for (int j = 0; j < 4; ++j)
          out[(size_t)(r0o + m * 16 + j) * NTOTB + col] = f2bf(acc[m][n][j]);
      }
  }
}

// ---------------- combine (sums the two split-K partials) ----------------
__global__ __launch_bounds__(256) void k_combine(const unsigned short* __restrict__ Oe0,
                                                 const unsigned short* __restrict__ Oe1,
                                                 const int* __restrict__ e01,
                                                 const float* __restrict__ p01,
                                                 const int* __restrict__ pos,
                                                 float* __restrict__ outp) {
  int t = blockIdx.x;
  int b = t / S_;
  int tid = threadIdx.x;
  float4 acc = {0.f, 0.f, 0.f, 0.f};
#pragma unroll
  for (int k = 0; k < TOPK; ++k) {
    int p = pos[t * 2 + k];
    if (p >= 0) {
      int e = e01[t * 2 + k];
      float w = p01[t * 2 + k];
      size_t row = (size_t)e * M_ + (size_t)b * CAP + p;
      us4 v0 = *(const us4*)&Oe0[row * H_ + tid * 4];
      us4 v1 = *(const us4*)&Oe1[row * H_ + tid * 4];
      acc.x += w * (bf2f(v0[0]) + bf2f(v1[0]));
      acc.y += w * (bf2f(v0[1]) + bf2f(v1[1]));
      acc.z += w * (bf2f(v0[2]) + bf2f(v1[2]));
      acc.w += w * (bf2f(v0[3]) + bf2f(v1[3]));
    }
  }
  *(float4*)&outp[(size_t)t * H_ + tid * 4] = acc;
}

extern "C" void kernel_launch(void* const* d_in, const int* in_sizes, int n_in,
                              void* d_out, int out_size, void* d_ws, size_t ws_size,
                              hipStream_t stream) {
  const float* hs = (const float*)d_in[0];
  const float* gw = (const float*)d_in[1];
  const float* w1 = (const float*)d_in[2];
  const float* w2 = (const float*)d_in[3];
  const float* w3 = (const float*)d_in[4];

  char* ws = (char*)d_ws;
  size_t off = 0;
  auto take = [&](size_t bytes) -> char* {
    char* p = ws + off;
    off += (bytes + 255) & ~(size_t)255;
    return p;
  };
  int*            e01  = (int*)take((size_t)NTOK * 2 * 4);
  float*          p01  = (float*)take((size_t)NTOK * 2 * 4);
  int*            pos  = (int*)take((size_t)NTOK * 2 * 4);
  int*            disp = (int*)take((size_t)E_ * B_ * CAP * 4);
  unsigned short* w13t = (unsigned short*)take((size_t)E_ * 2 * F_ * H_ * 2);
  unsigned short* w2t  = (unsigned short*)take((size_t)E_ * H_ * F_ * 2);
  unsigned short* hsb  = (unsigned short*)take((size_t)NTOK * H_ * 2);
  unsigned short* act  = (unsigned short*)take((size_t)E_ * M_ * F_ * 2);
  unsigned short* oe   = (unsigned short*)take((size_t)2 * E_ * M_ * H_ * 2);  // 2 split-K partials

  k_router<<<NTOK, 64, 0, stream>>>(hs, gw, e01, p01, hsb);
  k_positions<<<B_, 256, 0, stream>>>(e01, pos, disp);
  k_transpose<<<dim3(F_ / 64, H_ / 64, E_), 256, 0, stream>>>(w1, w13t, H_, F_, 1, 0, (size_t)2 * F_ * H_);
  k_transpose<<<dim3(F_ / 64, H_ / 64, E_), 256, 0, stream>>>(w3, w13t, H_, F_, 1, 1, (size_t)2 * F_ * H_);
  k_transpose<<<dim3(H_ / 64, F_ / 64, E_), 256, 0, stream>>>(w2, w2t, F_, H_, 0, 0, (size_t)H_ * F_);
  // GEMM1 (512 thr, round-14 schedule): gather-A from hsb; [M_ x 2F] over K=H, SwiGLU -> act
  k_gemm256<H_, true, true, M_ / 256, (2 * F_) / 256, 2 * F_, 1>
      <<<(M_ / 256) * ((2 * F_) / 256) * E_, 512, 0, stream>>>(hsb, w13t, act, disp);
  // GEMM2 (512 thr, round-14 schedule): [M_ x H] over K=F, split-K=2
  k_gemm256<F_, false, false, M_ / 256, H_ / 256, H_, 2>
      <<<(M_ / 256) * (H_ / 256) * E_ * 2, 512, 0, stream>>>(act, w2t, oe, disp);
  k_combine<<<NTOK, 256, 0, stream>>>(oe, oe + (size_t)E_ * M_ * H_, e01, p01, pos, (float*)d_out);
}